// Round 9
// baseline (259.459 us; speedup 1.0000x reference)
//
#include <hip/hip_runtime.h>
#include <hip/hip_bf16.h>

typedef __bf16 bf16;
typedef __attribute__((ext_vector_type(8))) __bf16 bf16x8;
typedef __attribute__((ext_vector_type(4))) __bf16 bf16x4;
typedef __attribute__((ext_vector_type(4))) float f32x4;
typedef __attribute__((ext_vector_type(16))) float f32x16;

#define LSP 4096   // H*W
#define CCH 256

__device__ __forceinline__ void gl2lds16(const bf16* g, bf16* l) {
  __builtin_amdgcn_global_load_lds(
      (const __attribute__((address_space(1))) unsigned int*)g,
      (__attribute__((address_space(3))) unsigned int*)l, 16, 0, 0);
}

__device__ __forceinline__ f32x4 mfma16(bf16x8 a, bf16x8 b, f32x4 c) {
  return __builtin_amdgcn_mfma_f32_16x16x32_bf16(a, b, c, 0, 0, 0);
}
__device__ __forceinline__ f32x16 mfma32(bf16x8 a, bf16x8 b, f32x16 c) {
  return __builtin_amdgcn_mfma_f32_32x32x16_bf16(a, b, c, 0, 0, 0);
}

// ---------------------------------------------------------------------------
// Weight f32 -> bf16. Wq,Wk direct; Wv TRANSPOSED (WvT[cin][och]); Wo direct;
// W1 INTERLEAVED and PRE-SCALED by g_ffn (row 2a = W1g[a], 2a+1 = W1g[a+512]);
// W2 direct.
// ---------------------------------------------------------------------------
__global__ __launch_bounds__(256) void cvt_w_kernel(
    const float* __restrict__ wq, const float* __restrict__ wk,
    const float* __restrict__ wv, const float* __restrict__ wo,
    const float* __restrict__ w1, const float* __restrict__ w2,
    const float* __restrict__ gff, bf16* __restrict__ out) {
  int e = blockIdx.x * 256 + threadIdx.x;   // grid 2560 -> 655360 exact
  if (e < 65536)        { out[e] = (bf16)wq[e]; }
  else if (e < 131072)  { out[e] = (bf16)wk[e - 65536]; }
  else if (e < 196608)  {
    int e2 = e - 131072;            // e2 = och*256 + cin
    int och = e2 >> 8, cin = e2 & 255;
    out[131072 + cin * 256 + och] = (bf16)wv[e2];   // WvT
  }
  else if (e < 262144)  { out[e] = (bf16)wo[e - 196608]; }
  else if (e < 524288)  {
    int e2 = e - 262144;            // m*256 + k, m in [0,1024)
    int m = e2 >> 8, k = e2 & 255;
    int mp = (m < 512) ? (2 * m) : (2 * (m - 512) + 1);
    out[262144 + mp * 256 + k] = (bf16)(w1[e2] * gff[k]);  // W1g interleaved
  }
  else                  { out[e] = (bf16)w2[e - 524288]; }
}

// ---------------------------------------------------------------------------
// Per-m FFN1 constants: cvec[0..511]=W1[m]@b_ffn+b1[m], [512..1023]=W1[m]@g_ffn,
// [1024..1535] / [1536..2047] = same for m+512. grid 4 x 256.
// ---------------------------------------------------------------------------
__global__ __launch_bounds__(256) void w1vec_kernel(
    const float* __restrict__ w1, const float* __restrict__ b1,
    const float* __restrict__ gff, const float* __restrict__ bff,
    float* __restrict__ cvec) {
  int m = blockIdx.x * 256 + threadIdx.x;   // 0..1023
  const float* row = w1 + (size_t)m * 256;
  float sb = 0.f, sg = 0.f;
  #pragma unroll 8
  for (int c = 0; c < 256; c += 4) {
    f32x4 w = *(const f32x4*)&row[c];
    f32x4 g = *(const f32x4*)&gff[c];
    f32x4 bb = *(const f32x4*)&bff[c];
    #pragma unroll
    for (int j = 0; j < 4; ++j) { sb += w[j] * bb[j]; sg += w[j] * g[j]; }
  }
  if (m < 512) {
    cvec[m] = sb + b1[m];
    cvec[512 + m] = sg;
  } else {
    cvec[512 + m] = sb + b1[m];       // 1024 + (m-512)
    cvec[1024 + m] = sg;              // 1536 + (m-512)
  }
}

// ---------------------------------------------------------------------------
// Tiled LayerNorm over channels. Input f32 [b][c][l]. Tile = 256c x 64l.
// ---------------------------------------------------------------------------
template <int DUAL>
__global__ __launch_bounds__(256) void ln_tile_kernel(
    const float* __restrict__ x, const float* __restrict__ gam,
    const float* __restrict__ bet, bf16* __restrict__ out_cl,
    bf16* __restrict__ out_lc) {
  const int l0 = blockIdx.x * 64;
  const int b  = blockIdx.y;
  const int tid = threadIdx.x;
  __shared__ bf16 Tt[256 * 64];          // 32 KB, swizzled
  __shared__ float red[2][16][64];       // 8 KB
  __shared__ float mu_s[64], rs_s[64];

  const float* px = x + (size_t)b * CCH * LSP + l0;
  const int colq = (tid & 15) * 4;
  f32x4 s = {0.f, 0.f, 0.f, 0.f}, q = {0.f, 0.f, 0.f, 0.f};
  #pragma unroll
  for (int it = 0; it < 16; ++it) {
    int c = it * 16 + (tid >> 4);
    f32x4 v = *(const f32x4*)&px[(size_t)c * LSP + colq];
    s += v;
    q += v * v;
    bf16x4 h;
    #pragma unroll
    for (int j = 0; j < 4; ++j) h[j] = (bf16)v[j];
    int colp = colq ^ (((c >> 3) & 7) << 3);
    *(bf16x4*)&Tt[c * 64 + colp] = h;
  }
  #pragma unroll
  for (int j = 0; j < 4; ++j) {
    red[0][tid >> 4][colq + j] = s[j];
    red[1][tid >> 4][colq + j] = q[j];
  }
  __syncthreads();
  if (tid < 64) {
    float S = 0.f, Q = 0.f;
    #pragma unroll
    for (int k = 0; k < 16; ++k) { S += red[0][k][tid]; Q += red[1][k][tid]; }
    float m = S * (1.f / 256.f);
    mu_s[tid] = m;
    rs_s[tid] = rsqrtf(Q * (1.f / 256.f) - m * m + 1e-5f);
  }
  __syncthreads();

  #pragma unroll
  for (int it = 0; it < 8; ++it) {
    int ch = it * 256 + tid;
    int c = ch >> 3, col8 = (ch & 7) * 8;
    int colp = col8 ^ (((c >> 3) & 7) << 3);
    bf16x8 h = *(const bf16x8*)&Tt[c * 64 + colp];
    f32x4 m0 = *(const f32x4*)&mu_s[col8];
    f32x4 m1 = *(const f32x4*)&mu_s[col8 + 4];
    f32x4 r0 = *(const f32x4*)&rs_s[col8];
    f32x4 r1 = *(const f32x4*)&rs_s[col8 + 4];
    float g = gam[c], be = bet[c];
    bf16x8 o;
    #pragma unroll
    for (int j = 0; j < 4; ++j) {
      o[j]     = (bf16)(((float)h[j] - m0[j]) * r0[j] * g + be);
      o[4 + j] = (bf16)(((float)h[4 + j] - m1[j]) * r1[j] * g + be);
    }
    *(bf16x8*)&out_cl[((size_t)b * CCH + c) * LSP + l0 + col8] = o;
  }

  if constexpr (DUAL) {
    #pragma unroll
    for (int it = 0; it < 8; ++it) {
      int ch = it * 256 + tid;
      int l = ch >> 5, cch = ch & 31;
      int c0 = cch * 8;
      int lp = l ^ ((cch & 7) << 3);
      float mu = mu_s[l], rs = rs_s[l];
      f32x4 g0 = *(const f32x4*)&gam[c0];
      f32x4 g1 = *(const f32x4*)&gam[c0 + 4];
      f32x4 b0 = *(const f32x4*)&bet[c0];
      f32x4 b1 = *(const f32x4*)&bet[c0 + 4];
      bf16x8 o;
      #pragma unroll
      for (int j = 0; j < 4; ++j) {
        float h0 = (float)Tt[(c0 + j) * 64 + lp];
        float h1 = (float)Tt[(c0 + 4 + j) * 64 + lp];
        o[j]     = (bf16)((h0 - mu) * rs * g0[j] + b0[j]);
        o[4 + j] = (bf16)((h1 - mu) * rs * g1[j] + b1[j]);
      }
      *(bf16x8*)&out_lc[((size_t)b * LSP + l0 + l) * CCH + c0] = o;
    }
  }
}

// ---------------------------------------------------------------------------
// Gram: G2part[chunk][b][j][i] = sum_{l in chunk} sar_cl[b][j][l]*opt_cl[b][i][l]
// ---------------------------------------------------------------------------
__global__ __launch_bounds__(256) void gram_kernel(
    const bf16* __restrict__ sar_cl, const bf16* __restrict__ opt_cl,
    float* __restrict__ part) {
  const int tile = blockIdx.x, chunk = blockIdx.y, b = blockIdx.z;
  const int tid = threadIdx.x, lane = tid & 63, w = tid >> 6;
  const int j0 = (tile >> 1) * 128 + (w >> 1) * 64;
  const int i0 = (tile & 1) * 128 + (w & 1) * 64;
  const int l0 = chunk * 1024;
  const bf16* sj = sar_cl + ((size_t)b * CCH + j0 + (lane & 31)) * LSP + l0;
  const bf16* oi = opt_cl + ((size_t)b * CCH + i0 + (lane & 31)) * LSP + l0;
  f32x16 acc[2][2];
  #pragma unroll
  for (int mt = 0; mt < 2; ++mt)
    #pragma unroll
    for (int nt = 0; nt < 2; ++nt)
      #pragma unroll
      for (int r = 0; r < 16; ++r) acc[mt][nt][r] = 0.f;
  #pragma unroll 4
  for (int ks = 0; ks < 64; ++ks) {
    int lofs = ks * 16 + (lane >> 5) * 8;
    bf16x8 a0 = *(const bf16x8*)&sj[lofs];
    bf16x8 a1 = *(const bf16x8*)&sj[32 * LSP + lofs];
    bf16x8 b0 = *(const bf16x8*)&oi[lofs];
    bf16x8 b1 = *(const bf16x8*)&oi[32 * LSP + lofs];
    acc[0][0] = mfma32(a0, b0, acc[0][0]);
    acc[0][1] = mfma32(a0, b1, acc[0][1]);
    acc[1][0] = mfma32(a1, b0, acc[1][0]);
    acc[1][1] = mfma32(a1, b1, acc[1][1]);
  }
  float* op = part + ((size_t)chunk * 16 + b) * 65536;
  #pragma unroll
  for (int mt = 0; mt < 2; ++mt)
    #pragma unroll
    for (int nt = 0; nt < 2; ++nt)
      #pragma unroll
      for (int r = 0; r < 16; ++r) {
        int row = j0 + mt * 32 + (r & 3) + 8 * (r >> 2) + 4 * (lane >> 5);
        int col = i0 + nt * 32 + (lane & 31);
        op[(size_t)row * 256 + col] = acc[mt][nt][r];
      }
}

// ---------------------------------------------------------------------------
// Reduce Gram partials (4 chunks) -> G2 bf16 [b][j][i]
// ---------------------------------------------------------------------------
__global__ __launch_bounds__(256) void greduce_kernel(
    const float* __restrict__ part, bf16* __restrict__ G2) {
  size_t e = ((size_t)blockIdx.x * 256 + threadIdx.x) * 8;  // grid 512
  float a[8];
  #pragma unroll
  for (int i = 0; i < 8; ++i) a[i] = 0.f;
  #pragma unroll
  for (int ch = 0; ch < 4; ++ch) {
    f32x4 p0 = *(const f32x4*)&part[ch * 1048576ull + e];
    f32x4 p1 = *(const f32x4*)&part[ch * 1048576ull + e + 4];
    #pragma unroll
    for (int i = 0; i < 4; ++i) { a[i] += p0[i]; a[4 + i] += p1[i]; }
  }
  bf16x8 o;
  #pragma unroll
  for (int i = 0; i < 8; ++i) o[i] = (bf16)a[i];
  *(bf16x8*)&G2[e] = o;
}

// ---------------------------------------------------------------------------
// Fold: per (b,h): M1[c][j] = sum_i Wq_h[c][i]*G2[j][i],
// S[c][d] = sum_j M1[c][j]*Wk_h[d][j], softmax rows -> P,
// UT[b][cin][h*32+c] = sum_d WvT[cin][h*32+d]*P[c][d].
// ---------------------------------------------------------------------------
__global__ __launch_bounds__(256) void fold2_kernel(
    const bf16* __restrict__ G2, const bf16* __restrict__ Wq,
    const bf16* __restrict__ Wk, const bf16* __restrict__ WvT,
    bf16* __restrict__ UT) {
  const int bh = blockIdx.x;
  const int b = bh >> 3, h = bh & 7;
  const int tid = threadIdx.x, lane = tid & 63, w = tid >> 6;
  __shared__ bf16 M1[32 * 256];
  __shared__ float Sp[4][1024];
  __shared__ float S[1024];
  __shared__ bf16 P[1024];

  const bf16* gq = Wq + (size_t)(h * 32) * 256;
  const bf16* g2b = G2 + (size_t)b * 65536;
  #pragma unroll
  for (int mt = 0; mt < 2; ++mt)
    #pragma unroll
    for (int nt = 0; nt < 4; ++nt) {
      f32x4 acc = {0.f, 0.f, 0.f, 0.f};
      #pragma unroll
      for (int ks = 0; ks < 8; ++ks) {
        bf16x8 a = *(const bf16x8*)&gq[(size_t)(mt * 16 + (lane & 15)) * 256 +
                                       ks * 32 + (lane >> 4) * 8];
        bf16x8 bb = *(const bf16x8*)&g2b[
            (size_t)(w * 64 + nt * 16 + (lane & 15)) * 256 + ks * 32 +
            (lane >> 4) * 8];
        acc = mfma16(a, bb, acc);
      }
      #pragma unroll
      for (int r = 0; r < 4; ++r)
        M1[(mt * 16 + (lane >> 4) * 4 + r) * 256 + w * 64 + nt * 16 +
           (lane & 15)] = (bf16)acc[r];
    }
  __syncthreads();

  const bf16* gk = Wk + (size_t)(h * 32) * 256;
  #pragma unroll
  for (int mt = 0; mt < 2; ++mt)
    #pragma unroll
    for (int dt = 0; dt < 2; ++dt) {
      f32x4 acc = {0.f, 0.f, 0.f, 0.f};
      #pragma unroll
      for (int kk = 0; kk < 2; ++kk) {
        bf16x8 a = *(const bf16x8*)&M1[(mt * 16 + (lane & 15)) * 256 + w * 64 +
                                       kk * 32 + (lane >> 4) * 8];
        bf16x8 bb = *(const bf16x8*)&gk[(size_t)(dt * 16 + (lane & 15)) * 256 +
                                        w * 64 + kk * 32 + (lane >> 4) * 8];
        acc = mfma16(a, bb, acc);
      }
      #pragma unroll
      for (int r = 0; r < 4; ++r)
        Sp[w][(mt * 16 + (lane >> 4) * 4 + r) * 32 + dt * 16 + (lane & 15)] =
            acc[r];
    }
  __syncthreads();
  #pragma unroll
  for (int i = 0; i < 4; ++i) {
    int e = tid + 256 * i;
    S[e] = (Sp[0][e] + Sp[1][e] + Sp[2][e] + Sp[3][e]) * 0.17677669529663687f;
  }
  __syncthreads();
  if (tid < 32) {
    float m = -1e30f;
    #pragma unroll
    for (int d = 0; d < 32; ++d) m = fmaxf(m, S[tid * 32 + d]);
    float sum = 0.f;
    float ex[32];
    #pragma unroll
    for (int d = 0; d < 32; ++d) {
      ex[d] = __expf(S[tid * 32 + d] - m);
      sum += ex[d];
    }
    float inv = 1.f / sum;
    #pragma unroll
    for (int d = 0; d < 32; ++d) P[tid * 32 + d] = (bf16)(ex[d] * inv);
  }
  __syncthreads();

  bf16x8 bfrag[2];
  #pragma unroll
  for (int ct = 0; ct < 2; ++ct)
    bfrag[ct] =
        *(const bf16x8*)&P[(ct * 16 + (lane & 15)) * 32 + (lane >> 4) * 8];
  bf16* outb = UT + (size_t)b * 65536 + h * 32;
  #pragma unroll
  for (int t = 0; t < 4; ++t) {
    int cin16 = w * 64 + t * 16;
    bf16x8 afrag = *(const bf16x8*)&WvT[(size_t)(cin16 + (lane & 15)) * 256 +
                                        h * 32 + (lane >> 4) * 8];
    #pragma unroll
    for (int ct = 0; ct < 2; ++ct) {
      f32x4 acc = {0.f, 0.f, 0.f, 0.f};
      acc = mfma16(afrag, bfrag[ct], acc);
      int c = ct * 16 + (lane & 15);
      int cinr = cin16 + (lane >> 4) * 4;
      #pragma unroll
      for (int r = 0; r < 4; ++r)
        outb[(size_t)(cinr + r) * 256 + c] = (bf16)acc[r];
    }
  }
}

// ---------------------------------------------------------------------------
// Small GEMM for Wfold: out bf16 [b][256][256] = Wo @ UT   (128x128 tiles)
// ---------------------------------------------------------------------------
__global__ __launch_bounds__(256) void wfold_kernel(
    const bf16* __restrict__ Aw, const bf16* __restrict__ Bx,
    bf16* __restrict__ outp) {
  const int tid = threadIdx.x;
  const int lane = tid & 63;
  const int wave = tid >> 6;
  const int wr = wave >> 1, wc = wave & 1;
  const int l0 = blockIdx.x * 128;
  const int m0 = blockIdx.y * 128;
  const int b  = blockIdx.z;
  constexpr int NB = 4096;
  __shared__ bf16 smem[4 * NB];
  bf16* As = smem;
  bf16* Bs = smem + 2 * NB;
  const bf16* Ag = Aw + (size_t)m0 * 256;
  const bf16* Bg = Bx + ((size_t)b * 256 + l0) * 256;
  auto stage = [&](int buf, int k0) {
    #pragma unroll
    for (int i = 0; i < 2; ++i) {
      int ch = i * 256 + tid;
      int r  = ch >> 2;
      int c8 = (ch & 3) * 8;
      gl2lds16(Ag + (size_t)r * 256 + k0 + c8, As + buf * NB + ch * 8);
      gl2lds16(Bg + (size_t)r * 256 + k0 + c8, Bs + buf * NB + ch * 8);
    }
  };
  f32x4 acc[4][4];
  #pragma unroll
  for (int mi = 0; mi < 4; ++mi)
    #pragma unroll
    for (int ni = 0; ni < 4; ++ni)
      #pragma unroll
      for (int r = 0; r < 4; ++r) acc[mi][ni][r] = 0.f;
  stage(0, 0);
  for (int kt = 0; kt < 8; ++kt) {
    __syncthreads();
    if (kt + 1 < 8) stage((kt + 1) & 1, (kt + 1) * 32);
    const bf16* Ab = As + (kt & 1) * NB;
    const bf16* Bb = Bs + (kt & 1) * NB;
    bf16x8 af[4], bfr[4];
    #pragma unroll
    for (int mi = 0; mi < 4; ++mi)
      af[mi] = *(const bf16x8*)&Ab[(wr * 64 + mi * 16 + (lane & 15)) * 32 +
                                   (lane >> 4) * 8];
    #pragma unroll
    for (int ni = 0; ni < 4; ++ni)
      bfr[ni] = *(const bf16x8*)&Bb[(wc * 64 + ni * 16 + (lane & 15)) * 32 +
                                    (lane >> 4) * 8];
    #pragma unroll
    for (int mi = 0; mi < 4; ++mi)
      #pragma unroll
      for (int ni = 0; ni < 4; ++ni)
        acc[mi][ni] = mfma16(af[mi], bfr[ni], acc[mi][ni]);
  }
  const int mq = m0 + wr * 64 + (lane >> 4) * 4;
  const int lq = l0 + wc * 64 + (lane & 15);
  #pragma unroll
  for (int mi = 0; mi < 4; ++mi)
    #pragma unroll
    for (int ni = 0; ni < 4; ++ni) {
      int l = lq + ni * 16, mb = mq + mi * 16;
      #pragma unroll
      for (int r = 0; r < 4; ++r)
        outp[((size_t)b * 256 + mb + r) * 256 + l] = (bf16)acc[mi][ni][r];
    }
}

// ---------------------------------------------------------------------------
// Fused x-GEMM + residual + LN-stats (M=256, N=64, K=256).
// ---------------------------------------------------------------------------
__global__ __launch_bounds__(256) void xgemm_stats_kernel(
    const bf16* __restrict__ Wfold, const bf16* __restrict__ sar_lc,
    const float* __restrict__ optical, bf16* __restrict__ xout,
    float* __restrict__ stats) {
  const int tid = threadIdx.x, lane = tid & 63, w = tid >> 6;
  const int l0 = blockIdx.x * 64;
  const int b  = blockIdx.y;
  __shared__ __align__(16) char smem[43520];
  bf16* X = (bf16*)smem;
  float* red = (float*)(smem + 40960);

  const bf16* Ag = Wfold + (size_t)b * 65536;
  const bf16* Bg = sar_lc + ((size_t)b * LSP + l0) * CCH;

  auto stage = [&](int buf, int k0) {
    bf16* As = (bf16*)(smem + buf * 16384);
    bf16* Bs = (bf16*)(smem + 32768 + buf * 4096);
    #pragma unroll
    for (int i = 0; i < 4; ++i) {
      int ch = i * 256 + tid;
      int r = ch >> 2, c8 = (ch & 3) * 8;
      gl2lds16(Ag + (size_t)r * 256 + k0 + c8, &As[ch * 8]);
    }
    {
      int r = tid >> 2, c8 = (tid & 3) * 8;
      gl2lds16(Bg + (size_t)r * 256 + k0 + c8, &Bs[tid * 8]);
    }
  };

  f32x4 acc[4][4];
  #pragma unroll
  for (int mi = 0; mi < 4; ++mi)
    #pragma unroll
    for (int ni = 0; ni < 4; ++ni)
      #pragma unroll
      for (int r = 0; r < 4; ++r) acc[mi][ni][r] = 0.f;

  stage(0, 0);
  for (int kt = 0; kt < 8; ++kt) {
    __syncthreads();
    if (kt < 7) stage((kt + 1) & 1, (kt + 1) * 32);
    const bf16* Ab = (const bf16*)(smem + (kt & 1) * 16384);
    const bf16* Bb = (const bf16*)(smem + 32768 + (kt & 1) * 4096);
    bf16x8 af[4], bfr[4];
    #pragma unroll
    for (int mi = 0; mi < 4; ++mi)
      af[mi] = *(const bf16x8*)&Ab[(w * 64 + mi * 16 + (lane & 15)) * 32 +
                                   (lane >> 4) * 8];
    #pragma unroll
    for (int ni = 0; ni < 4; ++ni)
      bfr[ni] = *(const bf16x8*)&Bb[(ni * 16 + (lane & 15)) * 32 +
                                    (lane >> 4) * 8];
    #pragma unroll
    for (int mi = 0; mi < 4; ++mi)
      #pragma unroll
      for (int ni = 0; ni < 4; ++ni)
        acc[mi][ni] = mfma16(af[mi], bfr[ni], acc[mi][ni]);
  }
  __syncthreads();   // all LDS frag reads done; As/Bs region reused as X

  const int cb = w * 64 + (lane >> 4) * 4;
  const int lb = lane & 15;
  float s[4], q[4];
  #pragma unroll
  for (int ni = 0; ni < 4; ++ni) { s[ni] = 0.f; q[ni] = 0.f; }
  #pragma unroll
  for (int mi = 0; mi < 4; ++mi)
    #pragma unroll
    for (int ni = 0; ni < 4; ++ni) {
      int c = cb + mi * 16, ll = lb + ni * 16;
      bf16x4 hx;
      #pragma unroll
      for (int r = 0; r < 4; ++r) {
        float v = acc[mi][ni][r] +
                  optical[((size_t)b * CCH + c + r) * LSP + l0 + ll];
        s[ni] += v; q[ni] += v * v;
        hx[r] = (bf16)v;
      }
      *(bf16x4*)&X[ll * 260 + c] = hx;
    }
  #pragma unroll
  for (int ni = 0; ni < 4; ++ni) {
    s[ni] += __shfl_xor(s[ni], 16);
    s[ni] += __shfl_xor(s[ni], 32);
    q[ni] += __shfl_xor(q[ni], 16);
    q[ni] += __shfl_xor(q[ni], 32);
  }
  if ((lane >> 4) == 0) {
    #pragma unroll
    for (int ni = 0; ni < 4; ++ni) {
      red[(0 * 4 + w) * 64 + ni * 16 + lb] = s[ni];
      red[(4 + w) * 64 + ni * 16 + lb] = q[ni];
    }
  }
  __syncthreads();
  if (tid < 64) {
    float S4 = red[0 * 64 + tid] + red[1 * 64 + tid] + red[2 * 64 + tid] +
               red[3 * 64 + tid];
    float Q4 = red[4 * 64 + tid] + red[5 * 64 + tid] + red[6 * 64 + tid] +
               red[7 * 64 + tid];
    float m = S4 * (1.f / 256.f);
    float rs = rsqrtf(Q4 * (1.f / 256.f) - m * m + 1e-5f);
    float* st = stats + ((size_t)b * LSP + l0 + tid) * 2;
    st[0] = m;
    st[1] = rs;
  }
  __syncthreads();
  #pragma unroll
  for (int it = 0; it < 8; ++it) {
    int cid = it * 256 + tid;            // 2048 chunks of 16B
    int l = cid >> 5, c0 = (cid & 31) * 8;
    bf16x8 v = *(const bf16x8*)&X[l * 260 + c0];
    *(bf16x8*)&xout[((size_t)b * LSP + l0 + l) * CCH + c0] = v;
  }
}

// ---------------------------------------------------------------------------
// FFN GEMM, occupancy-first variant: 256x128 tile, 8 waves (2m x 4n), BK=32
// double-buffered (48 KB LDS -> 2 blocks/CU), launch_bounds(512,4) caps VGPR
// at 128 (acc = 64 VGPR). Simple 2-barrier loop (m97 pattern); cross-block
// wave overlap hides stage latency (m114).
// LDS swizzle (BK=32, 64B rows): read chunk c' = (lane>>4) ^ ((row>>1)&3)
// -> 8 distinct bank-groups per 8 rows (2-way overall = free); staging
// pre-applies the same involution to the global source column.
// MODE 0 (KEL=256): A = W1g interleaved -> folded-LN + SimpleGate, bf16
//   [b][l][512] (128 gate ch per block via LDS transpose [128][136]).
// MODE 1 (KEL=512): A = W2 -> + b2 + res(bf16 x), f32 d_out [b][c][l]
//   (4 rounds of [64c][132] f32 LDS transpose).
// ---------------------------------------------------------------------------
template <int KEL, int MODE>
__global__ __launch_bounds__(512, 4) void ffn_gemm_kernel(
    const bf16* __restrict__ Aw, const bf16* __restrict__ Bx,
    void* __restrict__ outp, const bf16* __restrict__ resb,
    const float* __restrict__ bias, const float* __restrict__ stats) {
  __shared__ __align__(16) char smem[49152];
  const int tid = threadIdx.x;
  const int lane = tid & 63;
  const int wave = tid >> 6;
  const int wr = wave >> 2;        // 0..1 (m half: 128 rows)
  const int wc = wave & 3;         // 0..3 (n quarter: 32 cols)
  const int l0 = blockIdx.x * 128;
  const int m0 = blockIdx.y * 256;
  const int b  = blockIdx.z;

  const bf16* Ag = Aw + (size_t)m0 * KEL;
  const bf16* Bg = Bx + ((size_t)b * LSP + l0) * KEL;

  // A buf: 256x32 bf16 = 16 KB at smem + buf*16K; B buf: 128x32 = 8 KB at
  // smem + 32K + buf*8K.
  auto stage = [&](int buf, int kt) {
    char* la = smem + (buf << 14);
    char* lb2 = smem + 32768 + (buf << 13);
    #pragma unroll
    for (int i = 0; i < 2; ++i) {
      int qi = i * 512 + tid;                 // 0..1023 A-chunks
      int r = qi >> 2, c = qi & 3;
      int gc = c ^ ((r >> 1) & 3);
      gl2lds16(Ag + (size_t)r * KEL + kt * 32 + gc * 8,
               (bf16*)(la + qi * 16));
    }
    {
      int r = tid >> 2, c = tid & 3;          // 512 B-chunks
      int gc = c ^ ((r >> 1) & 3);
      gl2lds16(Bg + (size_t)r * KEL + kt * 32 + gc * 8,
               (bf16*)(lb2 + tid * 16));
    }
  };

  f32x4 acc[8][2];
  #pragma unroll
  for (int mi = 0; mi < 8; ++mi)
    #pragma unroll
    for (int ni = 0; ni < 2; ++ni)
      #pragma unroll
      for (int r = 0; r < 4; ++r) acc[mi][ni][r] = 0.f;

  constexpr int NK = KEL / 32;
  stage(0, 0);
  for (int kt = 0; kt < NK; ++kt) {
    __syncthreads();
    if (kt + 1 < NK) stage((kt + 1) & 1, kt + 1);
    const char* Ab = smem + ((kt & 1) << 14);
    const char* Bb = smem + 32768 + ((kt & 1) << 13);
    bf16x8 af[8], bf2[2];
    #pragma unroll
    for (int mi = 0; mi < 8; ++mi) {
      int row = wr * 128 + mi * 16 + (lane & 15);
      int c = (lane >> 4) ^ ((row >> 1) & 3);
      af[mi] = *(const bf16x8*)(Ab + row * 64 + c * 16);
    }
    #pragma unroll
    for (int ni = 0; ni < 2; ++ni) {
      int row = wc * 32 + ni * 16 + (lane & 15);
      int c = (lane >> 4) ^ ((row >> 1) & 3);
      bf2[ni] = *(const bf16x8*)(Bb + row * 64 + c * 16);
    }
    #pragma unroll
    for (int mi = 0; mi < 8; ++mi)
      #pragma unroll
      for (int ni = 0; ni < 2; ++ni)
        acc[mi][ni] = mfma16(af[mi], bf2[ni], acc[mi][ni]);
  }
  __syncthreads();   // staging region dead; reuse for epilogue

  const int qq = lane >> 4;
  if constexpr (MODE == 0) {
    // folded-LN + SimpleGate epilogue -> bf16 [b][l][512] (128 gc / block)
    bf16* g_lds = (bf16*)smem;               // [128 l][136] bf16 = 34.8 KB
    const int lq = wc * 32 + (lane & 15);
    const float* stb = stats + ((size_t)b * LSP + l0) * 2;
    float muv[2], rsv[2];
    #pragma unroll
    for (int ni = 0; ni < 2; ++ni) {
      int l = lq + ni * 16;
      muv[ni] = stb[l * 2];
      rsv[ni] = stb[l * 2 + 1];
    }
    #pragma unroll
    for (int mi = 0; mi < 8; ++mi) {
      int a0 = wr * 64 + mi * 8 + qq * 2;    // local gate row (0..127)
      int ag = (m0 >> 1) + a0;               // global gate row (0..511)
      float be1a = bias[ag],        ga1a = bias[512 + ag];
      float be2a = bias[1024 + ag], ga2a = bias[1536 + ag];
      float be1b = bias[ag + 1],        ga1b = bias[512 + ag + 1];
      float be2b = bias[1024 + ag + 1], ga2b = bias[1536 + ag + 1];
      #pragma unroll
      for (int ni = 0; ni < 2; ++ni) {
        int l = lq + ni * 16;
        float mrs = muv[ni] * rsv[ni];
        float h1a = rsv[ni] * acc[mi][ni][0] + be1a - mrs * ga1a;
        float h2a = rsv[ni] * acc[mi][ni][1] + be2a - mrs * ga2a;
        float h1b = rsv[ni] * acc[mi][ni][2] + be1b - mrs * ga1b;
        float h2b = rsv[ni] * acc[mi][ni][3] + be2b - mrs * ga2b;
        bf16 gv0 = (bf16)(h1a * h2a), gv1 = (bf16)(h1b * h2b);
        unsigned u = ((unsigned)*(unsigned short*)&gv1 << 16) |
                     (unsigned)*(unsigned short*)&gv0;
        *(unsigned*)&g_lds[l * 136 + a0] = u;
      }
    }
    __syncthreads();
    bf16* out = (bf16*)outp;
    const int gy = blockIdx.y * 128;
    #pragma unroll
    for (int it = 0; it < 4; ++it) {
      int cid = it * 512 + tid;              // 2048 chunks of 16B
      int l = cid >> 4, ch = cid & 15;
      bf16x8 v = *(const bf16x8*)&g_lds[l * 136 + ch * 8];
      *(bf16x8*)&out[((size_t)b * LSP + l0 + l) * 512 + gy + ch * 8] = v;
    }
  } else {
    // + b2 + residual -> f32 d_out [b][c][l]; 4 rounds of 64 c.
    float* lds_f = (float*)smem;             // [64 c][132] f32 = 33.8 KB
    float* out = (float*)outp;
    const int lq = wc * 32 + (lane & 15);
    #pragma unroll
    for (int round = 0; round < 4; ++round) {
      if (wr == (round >> 1)) {
        #pragma unroll
        for (int mj = 0; mj < 4; ++mj) {
          int mi = (round & 1) * 4 + mj;
          int c0r = mj * 16 + qq * 4;        // c within round (0..63)
          int cg = round * 64 + c0r;         // global c (0..255)
          f32x4 b4 = *(const f32x4*)&bias[cg];
          #pragma unroll
          for (int ni = 0; ni < 2; ++ni) {
            int l = lq + ni * 16;
            bf16x4 xr4 = *(const bf16x4*)&resb[((size_t)b * LSP + l0 + l) *
                                                   CCH + cg];
            #pragma unroll
            for (int r = 0; r < 4; ++r)
              lds_f[(c0r + r) * 132 + l] =
                  acc[mi][ni][r] + b4[r] + (float)xr4[r];
          }
        }
      }
      __syncthreads();
      #pragma unroll
      for (int it = 0; it < 4; ++it) {
        int cid = it * 512 + tid;            // 2048 chunks of 16B
        int c = cid >> 5, lch = cid & 31;
        f32x4 v = *(const f32x4*)&lds_f[c * 132 + lch * 4];
        *(f32x4*)&out[((size_t)b * CCH + round * 64 + c) * LSP + l0 +
                      lch * 4] = v;
      }
      __syncthreads();
    }
  }
}

// ---------------------------------------------------------------------------
extern "C" void kernel_launch(void* const* d_in, const int* in_sizes, int n_in,
                              void* d_out, int out_size, void* d_ws,
                              size_t ws_size, hipStream_t stream) {
  const float* optical = (const float*)d_in[0];
  const float* sar     = (const float*)d_in[1];
  const float* g_opt   = (const float*)d_in[2];
  const float* b_opt   = (const float*)d_in[3];
  const float* g_sar   = (const float*)d_in[4];
  const float* b_sar   = (const float*)d_in[5];
  const float* Wq      = (const float*)d_in[6];
  const float* Wk      = (const float*)d_in[7];
  const float* Wv      = (const float*)d_in[8];
  const float* Wo      = (const float*)d_in[9];
  const float* g_ffn   = (const float*)d_in[10];
  const float* b_ffn   = (const float*)d_in[11];
  const float* W1      = (const float*)d_in[12];
  const float* b1      = (const float*)d_in[13];
  const float* W2      = (const float*)d_in[14];
  const float* b2      = (const float*)d_in[15];

  char* ws = (char*)d_ws;
  bf16* wbf  = (bf16*)ws;
  bf16* Wqb  = wbf;
  bf16* Wkb  = wbf + 65536;
  bf16* WvTb = wbf + 131072;
  bf16* Wob  = wbf + 196608;
  bf16* W1b  = wbf + 262144;   // interleaved, pre-scaled by g_ffn
  bf16* W2b  = wbf + 524288;

  size_t off = 2ull * 1024 * 1024;
  const size_t T16 = 16ull * LSP * CCH * 2;  // 33.5 MB bf16 tensor
  bf16* opt_ncl = (bf16*)(ws + off); off += T16;
  bf16* sar_ncl = (bf16*)(ws + off); off += T16;
  bf16* sar_nlc = (bf16*)(ws + off); off += T16;
  bf16* xb      = (bf16*)(ws + off); off += T16;                   // x bf16
  float* stats  = (float*)(ws + off); off += 1ull * 1024 * 1024;   // 512KB+
  float* cvec   = (float*)(ws + off); off += 64 * 1024;            // 8KB
  float* Gpart  = (float*)(ws + off); off += 16ull * 1024 * 1024;  // 16 MB
  bf16* G2b     = (bf16*)(ws + off); off += 4ull * 1024 * 1024;
  bf16* UTb     = (bf16*)(ws + off); off += 2ull * 1024 * 1024;
  bf16* Wfoldb  = (bf16*)(ws + off); off += 2ull * 1024 * 1024;
  bf16* gbuf = opt_ncl;  // 67 MB overlay (opt_ncl+sar_ncl dead after gram)

  dim3 blk(256);
  cvt_w_kernel<<<2560, blk, 0, stream>>>(Wq, Wk, Wv, Wo, W1, W2, g_ffn, wbf);
  w1vec_kernel<<<4, blk, 0, stream>>>(W1, b1, g_ffn, b_ffn, cvec);
  ln_tile_kernel<0><<<dim3(64, 16), blk, 0, stream>>>(optical, g_opt, b_opt,
                                                      opt_ncl, nullptr);
  ln_tile_kernel<1><<<dim3(64, 16), blk, 0, stream>>>(sar, g_sar, b_sar,
                                                      sar_ncl, sar_nlc);
  gram_kernel<<<dim3(4, 4, 16), blk, 0, stream>>>(sar_ncl, opt_ncl, Gpart);
  greduce_kernel<<<512, blk, 0, stream>>>(Gpart, G2b);
  fold2_kernel<<<128, blk, 0, stream>>>(G2b, Wqb, Wkb, WvTb, UTb);
  wfold_kernel<<<dim3(2, 2, 16), blk, 0, stream>>>(Wob, UTb, Wfoldb);
  xgemm_stats_kernel<<<dim3(64, 16), blk, 0, stream>>>(Wfoldb, sar_nlc,
                                                       optical, xb, stats);
  ffn_gemm_kernel<256, 0><<<dim3(32, 4, 16), dim3(512), 0, stream>>>(
      W1b, xb, gbuf, nullptr, cvec, stats);
  ffn_gemm_kernel<512, 1><<<dim3(32, 1, 16), dim3(512), 0, stream>>>(
      W2b, gbuf, (float*)d_out, xb, b2, nullptr);
}